// Round 9
// baseline (78.426 us; speedup 1.0000x reference)
//
#include <hip/hip_runtime.h>
#include <hip/hip_bf16.h>

#define BB 8
#define CC 64
#define NN 4096
#define LOG2E 1.44269504088896340736f

typedef short bf16x8 __attribute__((ext_vector_type(8)));
typedef float f32x16 __attribute__((ext_vector_type(16)));
typedef unsigned int uint4v __attribute__((ext_vector_type(4)));

__device__ __forceinline__ unsigned cvt_pk_bf16(float lo, float hi) {
    unsigned r;
    asm("v_cvt_pk_bf16_f32 %0, %1, %2" : "=v"(r) : "v"(lo), "v"(hi));
    return r;
}

__device__ __forceinline__ float fast_exp2(float x) {
#if __has_builtin(__builtin_amdgcn_exp2f)
    return __builtin_amdgcn_exp2f(x);
#else
    return __builtin_exp2f(x);
#endif
}

// Workspace fragment layouts (all bf16 shorts):
//  qw   [b][n][8]
//  kfrag[b][tile32][lane64][8]  lane<32: K[key][d], lane>=32: zeros
//  vfrag[b][tile64][slab8][lane64][8]  slab = g*2+ct;
//    lane=(q,h) holds V^T[ch=ct*32+q][key=tile*64+g*16+h*8+i]

// ---------------------------------------------------------------------------
// Kernel 1: QKV projection, 5 groups x 128 position-tiles = 640 blocks.
// ---------------------------------------------------------------------------
__global__ __launch_bounds__(256) void qkv_kernel(
    const float* __restrict__ X,
    const float* __restrict__ Wq, const float* __restrict__ bq,
    const float* __restrict__ Wk, const float* __restrict__ bk,
    const float* __restrict__ Wv, const float* __restrict__ bv,
    unsigned short* __restrict__ qw, unsigned short* __restrict__ kfrag,
    unsigned short* __restrict__ vfrag)
{
    __shared__ float wbuf[64 * 16];
    __shared__ float bsh[16];
    __shared__ short vsh[16][264];

    const int t = threadIdx.x;
    const int grp = blockIdx.x % 5;
    const int tile = blockIdx.x / 5;
    const int b = tile >> 4;
    const int nb = (tile & 15) << 8;
    const int n = nb + t;

    if (grp == 0) {
        for (int i = t; i < 512; i += 256) {
            int o = i >> 6, c = i & 63;
            wbuf[c * 16 + o]     = Wq[i];
            wbuf[c * 16 + 8 + o] = Wk[i];
        }
        if (t < 8) { bsh[t] = bq[t]; bsh[8 + t] = bk[t]; }
    } else {
        const int cbase = (grp - 1) * 16;
        for (int i = t; i < 1024; i += 256) {
            int o = i >> 6, c = i & 63;
            wbuf[c * 16 + o] = Wv[(cbase + o) * 64 + c];
        }
        if (t < 16) bsh[t] = bv[cbase + t];
    }
    __syncthreads();

    float a[16];
    #pragma unroll
    for (int j = 0; j < 16; j++) a[j] = bsh[j];

    const float* xp = X + (size_t)b * CC * NN + n;
    for (int c = 0; c < 64; c++) {
        float xc = xp[(size_t)c * NN];
        const float4* w4 = (const float4*)&wbuf[c * 16];
        float4 w0 = w4[0], w1 = w4[1], w2 = w4[2], w3 = w4[3];
        a[0]  += w0.x * xc; a[1]  += w0.y * xc; a[2]  += w0.z * xc; a[3]  += w0.w * xc;
        a[4]  += w1.x * xc; a[5]  += w1.y * xc; a[6]  += w1.z * xc; a[7]  += w1.w * xc;
        a[8]  += w2.x * xc; a[9]  += w2.y * xc; a[10] += w2.z * xc; a[11] += w2.w * xc;
        a[12] += w3.x * xc; a[13] += w3.y * xc; a[14] += w3.z * xc; a[15] += w3.w * xc;
    }

    if (grp == 0) {
        alignas(16) __hip_bfloat16 qb8[8], kb8[8];
        #pragma unroll
        for (int d = 0; d < 8; d++) {
            qb8[d] = __float2bfloat16(a[d] * LOG2E);
            kb8[d] = __float2bfloat16(a[8 + d]);
        }
        const size_t g = (size_t)b * NN + n;
        *(int4*)(qw + g * 8) = *(const int4*)qb8;
        size_t kf = ((size_t)b * 128 + (n >> 5)) * 512;
        *(int4*)(kfrag + kf + (size_t)(n & 31) * 8) = *(const int4*)kb8;
        *(int4*)(kfrag + kf + (size_t)(32 + (n & 31)) * 8) = make_int4(0, 0, 0, 0);
    } else {
        const int cbase = (grp - 1) * 16;
        const int qb0 = cbase & 31, ct = cbase >> 5;
        #pragma unroll
        for (int j = 0; j < 16; j++)
            vsh[j][t] = __builtin_bit_cast(short, __float2bfloat16(a[j]));
        __syncthreads();
        #pragma unroll
        for (int rr = 0; rr < 2; ++rr) {
            int r = 2 * t + rr;
            int qq = r & 15, hh = (r >> 4) & 1, gg = (r >> 5) & 3, tau = r >> 7;
            int n0 = tau * 64 + gg * 16 + hh * 8;
            int4 val = *(const int4*)&vsh[qq][n0];
            int gtile = (nb >> 6) + tau;
            size_t dst = ((size_t)(b * 64 + gtile)) * 4096
                       + (size_t)(gg * 2 + ct) * 512
                       + (size_t)(32 * hh + qb0 + qq) * 8;
            *(int4*)(vfrag + dst) = val;
        }
    }
}

// ---------------------------------------------------------------------------
// Kernel 2: MFMA flash attention — no LDS, no barriers. 64 queries/wave,
// A-then-B serialized softmax so peak live VGPR ~158 fits launch_bounds
// (256,3) WITHOUT spills -> 3 waves/SIMD. K prefetched one 64-key tile
// ahead; V slabs loaded at half-tile start (~360cy before first use).
// KS=8 -> 4096 waves; XCD swizzle keeps each XCD's V slice L2-resident.
// ---------------------------------------------------------------------------
template<int KS, bool FUSE>
__global__ __launch_bounds__(256, 3) void attn_kernel(
    const unsigned short* __restrict__ qw,
    const unsigned short* __restrict__ kfrag,
    const unsigned short* __restrict__ vfrag,
    unsigned short* __restrict__ pout, float* __restrict__ pl,
    const float* __restrict__ X, const float* __restrict__ gamma,
    float* __restrict__ out)
{
    const int t = threadIdx.x;
    const int w = t >> 6, lane = t & 63;
    const int h = lane >> 5, q = lane & 31;

    const int nwg = gridDim.x;
    const int cpx = nwg >> 3;
    const int bid = (blockIdx.x & 7) * cpx + (blockIdx.x >> 3);

    const int qtile = bid & 15;
    const int b = (bid >> 4) & 7;
    const int ks = bid >> 7;

    const int qbase = qtile * 256 + w * 64;

    bf16x8 qfA = {}, qfB = {};
    if (h == 0) {
        qfA = *(const bf16x8*)(qw + ((size_t)b * NN + qbase + q) * 8);
        qfB = *(const bf16x8*)(qw + ((size_t)b * NN + qbase + 32 + q) * 8);
    }

    f32x16 accA0 = {}, accA1 = {}, accB0 = {}, accB1 = {};
    float lsumA = 0.f, lsumB = 0.f;

    const int NT = NN / KS / 64;
    const unsigned short* kb = kfrag + (size_t)b * 65536
                             + (size_t)ks * NT * 1024 + (size_t)lane * 8;
    const unsigned short* vbp = vfrag + (size_t)b * 262144
                              + (size_t)ks * NT * 4096 + (size_t)lane * 8;

    // one 32-key half-tile; kc = K fragment (in regs), vp = 4 V slabs.
    // Strict A-then-B: only one score/p set live at a time.
    auto halftile = [&](bf16x8 kc, const unsigned short* vp) {
        bf16x8 v0 = *(const bf16x8*)(vp);
        bf16x8 v1 = *(const bf16x8*)(vp + 512);
        bf16x8 v2 = *(const bf16x8*)(vp + 1024);
        bf16x8 v3 = *(const bf16x8*)(vp + 1536);

        // ---- subtile A ----
        {
            f32x16 sA = __builtin_amdgcn_mfma_f32_32x32x16_bf16(kc, qfA, (f32x16){}, 0, 0, 0);
            float pa[16];
            #pragma unroll
            for (int r = 0; r < 16; ++r) pa[r] = fast_exp2(sA[r]);
            float a0 = 0.f, a1 = 0.f;
            #pragma unroll
            for (int r = 0; r < 8; ++r) { a0 += pa[r]; a1 += pa[8 + r]; }
            lsumA += a0 + a1;
            unsigned ka[8];
            #pragma unroll
            for (int j = 0; j < 8; ++j) ka[j] = cvt_pk_bf16(pa[2 * j], pa[2 * j + 1]);
            __builtin_amdgcn_s_setprio(1);
            #pragma unroll
            for (int g2 = 0; g2 < 2; ++g2) {
                const unsigned* pg = &ka[4 * g2];
                auto ra = __builtin_amdgcn_permlane32_swap(pg[2], pg[0], false, false);
                auto rb = __builtin_amdgcn_permlane32_swap(pg[3], pg[1], false, false);
                uint4v bu = { ra[1], rb[1], ra[0], rb[0] };
                bf16x8 pf = __builtin_bit_cast(bf16x8, bu);
                bf16x8 vx = g2 ? v2 : v0;
                bf16x8 vy = g2 ? v3 : v1;
                accA0 = __builtin_amdgcn_mfma_f32_32x32x16_bf16(vx, pf, accA0, 0, 0, 0);
                accA1 = __builtin_amdgcn_mfma_f32_32x32x16_bf16(vy, pf, accA1, 0, 0, 0);
            }
            __builtin_amdgcn_s_setprio(0);
        }
        // ---- subtile B ----
        {
            f32x16 sB = __builtin_amdgcn_mfma_f32_32x32x16_bf16(kc, qfB, (f32x16){}, 0, 0, 0);
            float pb[16];
            #pragma unroll
            for (int r = 0; r < 16; ++r) pb[r] = fast_exp2(sB[r]);
            float b0 = 0.f, b1 = 0.f;
            #pragma unroll
            for (int r = 0; r < 8; ++r) { b0 += pb[r]; b1 += pb[8 + r]; }
            lsumB += b0 + b1;
            unsigned kb2[8];
            #pragma unroll
            for (int j = 0; j < 8; ++j) kb2[j] = cvt_pk_bf16(pb[2 * j], pb[2 * j + 1]);
            __builtin_amdgcn_s_setprio(1);
            #pragma unroll
            for (int g2 = 0; g2 < 2; ++g2) {
                const unsigned* pg = &kb2[4 * g2];
                auto ra = __builtin_amdgcn_permlane32_swap(pg[2], pg[0], false, false);
                auto rb = __builtin_amdgcn_permlane32_swap(pg[3], pg[1], false, false);
                uint4v bu = { ra[1], rb[1], ra[0], rb[0] };
                bf16x8 pf = __builtin_bit_cast(bf16x8, bu);
                bf16x8 vx = g2 ? v2 : v0;
                bf16x8 vy = g2 ? v3 : v1;
                accB0 = __builtin_amdgcn_mfma_f32_32x32x16_bf16(vx, pf, accB0, 0, 0, 0);
                accB1 = __builtin_amdgcn_mfma_f32_32x32x16_bf16(vy, pf, accB1, 0, 0, 0);
            }
            __builtin_amdgcn_s_setprio(0);
        }
    };

    bf16x8 kc0 = *(const bf16x8*)kb;
    bf16x8 kc1 = *(const bf16x8*)(kb + 512);

    for (int it = 0; it < NT; ++it) {
        const int nit = (it + 1 < NT) ? it + 1 : it;
        const unsigned short* knp = kb + (size_t)nit * 1024;
        bf16x8 kn0 = *(const bf16x8*)knp;
        bf16x8 kn1 = *(const bf16x8*)(knp + 512);

        const unsigned short* vp = vbp + (size_t)it * 4096;
        halftile(kc0, vp);           // keys 0..31 of tile, slabs 0..3
        halftile(kc1, vp + 2048);    // keys 32..63, slabs 4..7

        kc0 = kn0;
        kc1 = kn1;
    }

    auto rsA = __builtin_amdgcn_permlane32_swap(__builtin_bit_cast(unsigned, lsumA),
                                                __builtin_bit_cast(unsigned, lsumA), false, false);
    float ltotA = __builtin_bit_cast(float, rsA[0]) + __builtin_bit_cast(float, rsA[1]);
    auto rsB = __builtin_amdgcn_permlane32_swap(__builtin_bit_cast(unsigned, lsumB),
                                                __builtin_bit_cast(unsigned, lsumB), false, false);
    float ltotB = __builtin_bit_cast(float, rsB[0]) + __builtin_bit_cast(float, rsB[1]);

    const float gm = FUSE ? gamma[0] : 0.f;

    #pragma unroll
    for (int sub = 0; sub < 2; ++sub) {
        const int n = qbase + sub * 32 + q;
        const float ltot = sub ? ltotB : ltotA;
        const f32x16& a0 = sub ? accB0 : accA0;
        const f32x16& a1 = sub ? accB1 : accA1;
        if (FUSE) {
            const float inv = 1.f / ltot;
            #pragma unroll
            for (int ct = 0; ct < 2; ++ct) {
                const f32x16& a = ct ? a1 : a0;
                #pragma unroll
                for (int r = 0; r < 16; ++r) {
                    int c = ct * 32 + (r & 3) + 8 * (r >> 2) + 4 * h;
                    size_t idx = ((size_t)(b * CC + c)) * NN + n;
                    out[idx] = X[idx] + gm * a[r] * inv;
                }
            }
        } else {
            unsigned short* po = pout + (size_t)ks * BB * CC * NN;
            #pragma unroll
            for (int ct = 0; ct < 2; ++ct) {
                const f32x16& a = ct ? a1 : a0;
                #pragma unroll
                for (int r = 0; r < 16; ++r) {
                    int c = ct * 32 + (r & 3) + 8 * (r >> 2) + 4 * h;
                    po[((size_t)(b * CC + c)) * NN + n] =
                        __builtin_bit_cast(unsigned short, __float2bfloat16(a[r]));
                }
            }
            if (h == 0) pl[((size_t)(ks * BB + b)) * NN + n] = ltot;
        }
    }
}

// ---------------------------------------------------------------------------
// Kernel 3: combine KS key-splits (bf16 partials) + epilogue.
// ---------------------------------------------------------------------------
template<int KS>
__global__ __launch_bounds__(256) void combine_kernel(
    const unsigned short* __restrict__ pout, const float* __restrict__ pl,
    const float* __restrict__ X, const float* __restrict__ gamma,
    float* __restrict__ out)
{
    const int idx = blockIdx.x * 256 + threadIdx.x;
    const int n4 = idx & 1023;
    const int c  = (idx >> 10) & 63;
    const int b  = idx >> 16;
    const int n0 = n4 * 4;
    const float gm = gamma[0];
    const size_t base = ((size_t)(b * CC + c)) * NN + n0;

    float4 s = make_float4(0.f, 0.f, 0.f, 0.f);
    float4 L = make_float4(0.f, 0.f, 0.f, 0.f);
    #pragma unroll
    for (int ks = 0; ks < KS; ++ks) {
        ushort4 sv = *(const ushort4*)(pout + (size_t)ks * BB * CC * NN + base);
        float4 lv = *(const float4*)(pl + ((size_t)(ks * BB + b)) * NN + n0);
        s.x += __bfloat162float(__builtin_bit_cast(__hip_bfloat16, sv.x));
        s.y += __bfloat162float(__builtin_bit_cast(__hip_bfloat16, sv.y));
        s.z += __bfloat162float(__builtin_bit_cast(__hip_bfloat16, sv.z));
        s.w += __bfloat162float(__builtin_bit_cast(__hip_bfloat16, sv.w));
        L.x += lv.x; L.y += lv.y; L.z += lv.z; L.w += lv.w;
    }
    float4 x = *(const float4*)(X + base);
    float4 o;
    o.x = x.x + gm * s.x / L.x;
    o.y = x.y + gm * s.y / L.y;
    o.z = x.z + gm * s.z / L.z;
    o.w = x.w + gm * s.w / L.w;
    *(float4*)(out + base) = o;
}

// ---------------------------------------------------------------------------
extern "C" void kernel_launch(void* const* d_in, const int* in_sizes, int n_in,
                              void* d_out, int out_size, void* d_ws, size_t ws_size,
                              hipStream_t stream) {
    const float* X  = (const float*)d_in[0];
    const float* Wq = (const float*)d_in[1];
    const float* bq = (const float*)d_in[2];
    const float* Wk = (const float*)d_in[3];
    const float* bk = (const float*)d_in[4];
    const float* Wv = (const float*)d_in[5];
    const float* bv = (const float*)d_in[6];
    const float* gm = (const float*)d_in[7];
    float* out = (float*)d_out;

    unsigned short* qw    = (unsigned short*)d_ws;
    unsigned short* kfrag = qw + (size_t)BB * NN * 8;
    unsigned short* vfrag = kfrag + (size_t)BB * 128 * 512;
    unsigned short* pout  = vfrag + (size_t)BB * 64 * 4096;
    float* pl = (float*)(pout + (size_t)8 * BB * CC * NN);

    const size_t qkv_bytes = ((size_t)BB * NN * 8 + (size_t)BB * 128 * 512
                            + (size_t)BB * 64 * 4096) * 2;
    const size_t need8 = qkv_bytes + (size_t)8 * BB * CC * NN * 2 + (size_t)8 * BB * NN * 4;
    const size_t need4 = qkv_bytes + (size_t)4 * BB * CC * NN * 2 + (size_t)4 * BB * NN * 4;

    qkv_kernel<<<dim3(640), dim3(256), 0, stream>>>(X, Wq, bq, Wk, bk, Wv, bv, qw, kfrag, vfrag);

    if (ws_size >= need8) {
        attn_kernel<8, false><<<dim3(1024), dim3(256), 0, stream>>>(
            qw, kfrag, vfrag, pout, pl, X, gm, out);
        combine_kernel<8><<<dim3((BB * CC * NN / 4) / 256), dim3(256), 0, stream>>>(
            pout, pl, X, gm, out);
    } else if (ws_size >= need4) {
        float* pl4 = (float*)(pout + (size_t)4 * BB * CC * NN);
        attn_kernel<4, false><<<dim3(512), dim3(256), 0, stream>>>(
            qw, kfrag, vfrag, pout, pl4, X, gm, out);
        combine_kernel<4><<<dim3((BB * CC * NN / 4) / 256), dim3(256), 0, stream>>>(
            pout, pl4, X, gm, out);
    } else {
        attn_kernel<1, true><<<dim3(128), dim3(256), 0, stream>>>(
            qw, kfrag, vfrag, nullptr, nullptr, X, gm, out);
    }
}

// Round 10
// 55.691 us; speedup vs baseline: 1.4082x; 1.4082x over previous
//
#include <hip/hip_runtime.h>
#include <hip/hip_bf16.h>

#define BB 8
#define CC 64
#define NN 4096
#define LOG2E 1.44269504088896340736f

typedef short bf16x8 __attribute__((ext_vector_type(8)));
typedef float f32x16 __attribute__((ext_vector_type(16)));
typedef unsigned int uint4v __attribute__((ext_vector_type(4)));

__device__ __forceinline__ unsigned cvt_pk_bf16(float lo, float hi) {
    unsigned r;
    asm("v_cvt_pk_bf16_f32 %0, %1, %2" : "=v"(r) : "v"(lo), "v"(hi));
    return r;
}

__device__ __forceinline__ float fast_exp2(float x) {
#if __has_builtin(__builtin_amdgcn_exp2f)
    return __builtin_amdgcn_exp2f(x);
#else
    return __builtin_exp2f(x);
#endif
}

// Workspace fragment layouts (all bf16 shorts):
//  qw   [b][n][8]
//  kfrag[b][tile32][lane64][8]  lane<32: K[key][d], lane>=32: zeros
//  vfrag[b][tile64][slab8][lane64][8]  slab = g*2+ct;
//    lane=(q,h) holds V^T[ch=ct*32+q][key=tile*64+g*16+h*8+i]

// ---------------------------------------------------------------------------
// Kernel 1: QKV projection, 5 groups x 128 position-tiles = 640 blocks.
// ---------------------------------------------------------------------------
__global__ __launch_bounds__(256) void qkv_kernel(
    const float* __restrict__ X,
    const float* __restrict__ Wq, const float* __restrict__ bq,
    const float* __restrict__ Wk, const float* __restrict__ bk,
    const float* __restrict__ Wv, const float* __restrict__ bv,
    unsigned short* __restrict__ qw, unsigned short* __restrict__ kfrag,
    unsigned short* __restrict__ vfrag)
{
    __shared__ float wbuf[64 * 16];
    __shared__ float bsh[16];
    __shared__ short vsh[16][264];

    const int t = threadIdx.x;
    const int grp = blockIdx.x % 5;
    const int tile = blockIdx.x / 5;
    const int b = tile >> 4;
    const int nb = (tile & 15) << 8;
    const int n = nb + t;

    if (grp == 0) {
        for (int i = t; i < 512; i += 256) {
            int o = i >> 6, c = i & 63;
            wbuf[c * 16 + o]     = Wq[i];
            wbuf[c * 16 + 8 + o] = Wk[i];
        }
        if (t < 8) { bsh[t] = bq[t]; bsh[8 + t] = bk[t]; }
    } else {
        const int cbase = (grp - 1) * 16;
        for (int i = t; i < 1024; i += 256) {
            int o = i >> 6, c = i & 63;
            wbuf[c * 16 + o] = Wv[(cbase + o) * 64 + c];
        }
        if (t < 16) bsh[t] = bv[cbase + t];
    }
    __syncthreads();

    float a[16];
    #pragma unroll
    for (int j = 0; j < 16; j++) a[j] = bsh[j];

    const float* xp = X + (size_t)b * CC * NN + n;
    for (int c = 0; c < 64; c++) {
        float xc = xp[(size_t)c * NN];
        const float4* w4 = (const float4*)&wbuf[c * 16];
        float4 w0 = w4[0], w1 = w4[1], w2 = w4[2], w3 = w4[3];
        a[0]  += w0.x * xc; a[1]  += w0.y * xc; a[2]  += w0.z * xc; a[3]  += w0.w * xc;
        a[4]  += w1.x * xc; a[5]  += w1.y * xc; a[6]  += w1.z * xc; a[7]  += w1.w * xc;
        a[8]  += w2.x * xc; a[9]  += w2.y * xc; a[10] += w2.z * xc; a[11] += w2.w * xc;
        a[12] += w3.x * xc; a[13] += w3.y * xc; a[14] += w3.z * xc; a[15] += w3.w * xc;
    }

    if (grp == 0) {
        alignas(16) __hip_bfloat16 qb8[8], kb8[8];
        #pragma unroll
        for (int d = 0; d < 8; d++) {
            qb8[d] = __float2bfloat16(a[d] * LOG2E);
            kb8[d] = __float2bfloat16(a[8 + d]);
        }
        const size_t g = (size_t)b * NN + n;
        *(int4*)(qw + g * 8) = *(const int4*)qb8;
        size_t kf = ((size_t)b * 128 + (n >> 5)) * 512;
        *(int4*)(kfrag + kf + (size_t)(n & 31) * 8) = *(const int4*)kb8;
        *(int4*)(kfrag + kf + (size_t)(32 + (n & 31)) * 8) = make_int4(0, 0, 0, 0);
    } else {
        const int cbase = (grp - 1) * 16;
        const int qb0 = cbase & 31, ct = cbase >> 5;
        #pragma unroll
        for (int j = 0; j < 16; j++)
            vsh[j][t] = __builtin_bit_cast(short, __float2bfloat16(a[j]));
        __syncthreads();
        #pragma unroll
        for (int rr = 0; rr < 2; ++rr) {
            int r = 2 * t + rr;
            int qq = r & 15, hh = (r >> 4) & 1, gg = (r >> 5) & 3, tau = r >> 7;
            int n0 = tau * 64 + gg * 16 + hh * 8;
            int4 val = *(const int4*)&vsh[qq][n0];
            int gtile = (nb >> 6) + tau;
            size_t dst = ((size_t)(b * 64 + gtile)) * 4096
                       + (size_t)(gg * 2 + ct) * 512
                       + (size_t)(32 * hh + qb0 + qq) * 8;
            *(int4*)(vfrag + dst) = val;
        }
    }
}

// ---------------------------------------------------------------------------
// Kernel 2: MFMA flash attention — no LDS, no barriers. EXACT R7 structure
// (interleaved A/B softmax per 32-key phase, K prefetched one 64-key tile
// ahead, all 8 V slabs issued at tile top, (256,2) so compiler lands ~120
// total regs -> HW allows 4 waves/SIMD). KS=8 -> 4096 waves removes the
// grid limit; XCD swizzle keeps each XCD's key-split V slice L2-resident.
// ---------------------------------------------------------------------------
template<int KS, bool FUSE>
__global__ __launch_bounds__(256, 2) void attn_kernel(
    const unsigned short* __restrict__ qw,
    const unsigned short* __restrict__ kfrag,
    const unsigned short* __restrict__ vfrag,
    unsigned short* __restrict__ pout, float* __restrict__ pl,
    const float* __restrict__ X, const float* __restrict__ gamma,
    float* __restrict__ out)
{
    const int t = threadIdx.x;
    const int w = t >> 6, lane = t & 63;
    const int h = lane >> 5, q = lane & 31;

    const int nwg = gridDim.x;
    const int cpx = nwg >> 3;
    const int bid = (blockIdx.x & 7) * cpx + (blockIdx.x >> 3);

    const int qtile = bid & 15;
    const int b = (bid >> 4) & 7;
    const int ks = bid >> 7;

    const int qbase = qtile * 256 + w * 64;

    bf16x8 qfA = {}, qfB = {};
    if (h == 0) {
        qfA = *(const bf16x8*)(qw + ((size_t)b * NN + qbase + q) * 8);
        qfB = *(const bf16x8*)(qw + ((size_t)b * NN + qbase + 32 + q) * 8);
    }

    f32x16 accA0 = {}, accA1 = {}, accB0 = {}, accB1 = {};
    float lsumA = 0.f, lsumB = 0.f;

    const int NT = NN / KS / 64;
    const unsigned short* kb = kfrag + (size_t)b * 65536
                             + (size_t)ks * NT * 1024 + (size_t)lane * 8;
    const unsigned short* vbp = vfrag + (size_t)b * 262144
                              + (size_t)ks * NT * 4096 + (size_t)lane * 8;

    // one 32-key phase: QK scores already computed (sA,sB); consume 4 V slabs
    auto phase = [&](const f32x16& sA, const f32x16& sB,
                     bf16x8 va, bf16x8 vb2, bf16x8 vc, bf16x8 vd) {
        float pa[16], pb[16];
        #pragma unroll
        for (int r = 0; r < 16; ++r) { pa[r] = fast_exp2(sA[r]); pb[r] = fast_exp2(sB[r]); }
        {
            float a0 = 0.f, a1 = 0.f, b0 = 0.f, b1 = 0.f;
            #pragma unroll
            for (int r = 0; r < 8; ++r) {
                a0 += pa[r]; a1 += pa[8 + r];
                b0 += pb[r]; b1 += pb[8 + r];
            }
            lsumA += a0 + a1;
            lsumB += b0 + b1;
        }
        unsigned ka[8], kb2[8];
        #pragma unroll
        for (int j = 0; j < 8; ++j) {
            ka[j]  = cvt_pk_bf16(pa[2 * j], pa[2 * j + 1]);
            kb2[j] = cvt_pk_bf16(pb[2 * j], pb[2 * j + 1]);
        }
        __builtin_amdgcn_s_setprio(1);
        #pragma unroll
        for (int g2 = 0; g2 < 2; ++g2) {
            const unsigned* pga = &ka[4 * g2];
            auto ra = __builtin_amdgcn_permlane32_swap(pga[2], pga[0], false, false);
            auto rb = __builtin_amdgcn_permlane32_swap(pga[3], pga[1], false, false);
            uint4v bua = { ra[1], rb[1], ra[0], rb[0] };
            bf16x8 pfA = __builtin_bit_cast(bf16x8, bua);
            const unsigned* pgb = &kb2[4 * g2];
            auto rc = __builtin_amdgcn_permlane32_swap(pgb[2], pgb[0], false, false);
            auto rd = __builtin_amdgcn_permlane32_swap(pgb[3], pgb[1], false, false);
            uint4v bub = { rc[1], rd[1], rc[0], rd[0] };
            bf16x8 pfB = __builtin_bit_cast(bf16x8, bub);

            bf16x8 vx = g2 ? vc : va;
            bf16x8 vy = g2 ? vd : vb2;
            accA0 = __builtin_amdgcn_mfma_f32_32x32x16_bf16(vx, pfA, accA0, 0, 0, 0);
            accA1 = __builtin_amdgcn_mfma_f32_32x32x16_bf16(vy, pfA, accA1, 0, 0, 0);
            accB0 = __builtin_amdgcn_mfma_f32_32x32x16_bf16(vx, pfB, accB0, 0, 0, 0);
            accB1 = __builtin_amdgcn_mfma_f32_32x32x16_bf16(vy, pfB, accB1, 0, 0, 0);
        }
        __builtin_amdgcn_s_setprio(0);
    };

    bf16x8 kc0 = *(const bf16x8*)kb;
    bf16x8 kc1 = *(const bf16x8*)(kb + 512);

    for (int it = 0; it < NT; ++it) {
        const unsigned short* vp = vbp + (size_t)it * 4096;
        bf16x8 v0 = *(const bf16x8*)(vp);
        bf16x8 v1 = *(const bf16x8*)(vp + 512);
        bf16x8 v2 = *(const bf16x8*)(vp + 1024);
        bf16x8 v3 = *(const bf16x8*)(vp + 1536);
        bf16x8 v4 = *(const bf16x8*)(vp + 2048);
        bf16x8 v5 = *(const bf16x8*)(vp + 2560);
        bf16x8 v6 = *(const bf16x8*)(vp + 3072);
        bf16x8 v7 = *(const bf16x8*)(vp + 3584);

        const int nit = (it + 1 < NT) ? it + 1 : it;   // clamped, branchless
        const unsigned short* knp = kb + (size_t)nit * 1024;
        bf16x8 kn0 = *(const bf16x8*)knp;
        bf16x8 kn1 = *(const bf16x8*)(knp + 512);

        // phase 0: keys 0..31 of the tile
        {
            f32x16 sA = __builtin_amdgcn_mfma_f32_32x32x16_bf16(kc0, qfA, (f32x16){}, 0, 0, 0);
            f32x16 sB = __builtin_amdgcn_mfma_f32_32x32x16_bf16(kc0, qfB, (f32x16){}, 0, 0, 0);
            phase(sA, sB, v0, v1, v2, v3);
        }
        // phase 1: keys 32..63
        {
            f32x16 sA = __builtin_amdgcn_mfma_f32_32x32x16_bf16(kc1, qfA, (f32x16){}, 0, 0, 0);
            f32x16 sB = __builtin_amdgcn_mfma_f32_32x32x16_bf16(kc1, qfB, (f32x16){}, 0, 0, 0);
            phase(sA, sB, v4, v5, v6, v7);
        }
        kc0 = kn0;
        kc1 = kn1;
    }

    auto rsA = __builtin_amdgcn_permlane32_swap(__builtin_bit_cast(unsigned, lsumA),
                                                __builtin_bit_cast(unsigned, lsumA), false, false);
    float ltotA = __builtin_bit_cast(float, rsA[0]) + __builtin_bit_cast(float, rsA[1]);
    auto rsB = __builtin_amdgcn_permlane32_swap(__builtin_bit_cast(unsigned, lsumB),
                                                __builtin_bit_cast(unsigned, lsumB), false, false);
    float ltotB = __builtin_bit_cast(float, rsB[0]) + __builtin_bit_cast(float, rsB[1]);

    const float gm = FUSE ? gamma[0] : 0.f;

    #pragma unroll
    for (int sub = 0; sub < 2; ++sub) {
        const int n = qbase + sub * 32 + q;
        const float ltot = sub ? ltotB : ltotA;
        const f32x16& a0 = sub ? accB0 : accA0;
        const f32x16& a1 = sub ? accB1 : accA1;
        if (FUSE) {
            const float inv = 1.f / ltot;
            #pragma unroll
            for (int ct = 0; ct < 2; ++ct) {
                const f32x16& a = ct ? a1 : a0;
                #pragma unroll
                for (int r = 0; r < 16; ++r) {
                    int c = ct * 32 + (r & 3) + 8 * (r >> 2) + 4 * h;
                    size_t idx = ((size_t)(b * CC + c)) * NN + n;
                    out[idx] = X[idx] + gm * a[r] * inv;
                }
            }
        } else {
            unsigned short* po = pout + (size_t)ks * BB * CC * NN;
            #pragma unroll
            for (int ct = 0; ct < 2; ++ct) {
                const f32x16& a = ct ? a1 : a0;
                #pragma unroll
                for (int r = 0; r < 16; ++r) {
                    int c = ct * 32 + (r & 3) + 8 * (r >> 2) + 4 * h;
                    po[((size_t)(b * CC + c)) * NN + n] =
                        __builtin_bit_cast(unsigned short, __float2bfloat16(a[r]));
                }
            }
            if (h == 0) pl[((size_t)(ks * BB + b)) * NN + n] = ltot;
        }
    }
}

// ---------------------------------------------------------------------------
// Kernel 3: combine KS key-splits (bf16 partials) + epilogue.
// ---------------------------------------------------------------------------
template<int KS>
__global__ __launch_bounds__(256) void combine_kernel(
    const unsigned short* __restrict__ pout, const float* __restrict__ pl,
    const float* __restrict__ X, const float* __restrict__ gamma,
    float* __restrict__ out)
{
    const int idx = blockIdx.x * 256 + threadIdx.x;
    const int n4 = idx & 1023;
    const int c  = (idx >> 10) & 63;
    const int b  = idx >> 16;
    const int n0 = n4 * 4;
    const float gm = gamma[0];
    const size_t base = ((size_t)(b * CC + c)) * NN + n0;

    float4 s = make_float4(0.f, 0.f, 0.f, 0.f);
    float4 L = make_float4(0.f, 0.f, 0.f, 0.f);
    #pragma unroll
    for (int ks = 0; ks < KS; ++ks) {
        ushort4 sv = *(const ushort4*)(pout + (size_t)ks * BB * CC * NN + base);
        float4 lv = *(const float4*)(pl + ((size_t)(ks * BB + b)) * NN + n0);
        s.x += __bfloat162float(__builtin_bit_cast(__hip_bfloat16, sv.x));
        s.y += __bfloat162float(__builtin_bit_cast(__hip_bfloat16, sv.y));
        s.z += __bfloat162float(__builtin_bit_cast(__hip_bfloat16, sv.z));
        s.w += __bfloat162float(__builtin_bit_cast(__hip_bfloat16, sv.w));
        L.x += lv.x; L.y += lv.y; L.z += lv.z; L.w += lv.w;
    }
    float4 x = *(const float4*)(X + base);
    float4 o;
    o.x = x.x + gm * s.x / L.x;
    o.y = x.y + gm * s.y / L.y;
    o.z = x.z + gm * s.z / L.z;
    o.w = x.w + gm * s.w / L.w;
    *(float4*)(out + base) = o;
}

// ---------------------------------------------------------------------------
extern "C" void kernel_launch(void* const* d_in, const int* in_sizes, int n_in,
                              void* d_out, int out_size, void* d_ws, size_t ws_size,
                              hipStream_t stream) {
    const float* X  = (const float*)d_in[0];
    const float* Wq = (const float*)d_in[1];
    const float* bq = (const float*)d_in[2];
    const float* Wk = (const float*)d_in[3];
    const float* bk = (const float*)d_in[4];
    const float* Wv = (const float*)d_in[5];
    const float* bv = (const float*)d_in[6];
    const float* gm = (const float*)d_in[7];
    float* out = (float*)d_out;

    unsigned short* qw    = (unsigned short*)d_ws;
    unsigned short* kfrag = qw + (size_t)BB * NN * 8;
    unsigned short* vfrag = kfrag + (size_t)BB * 128 * 512;
    unsigned short* pout  = vfrag + (size_t)BB * 64 * 4096;
    float* pl = (float*)(pout + (size_t)8 * BB * CC * NN);

    const size_t qkv_bytes = ((size_t)BB * NN * 8 + (size_t)BB * 128 * 512
                            + (size_t)BB * 64 * 4096) * 2;
    const size_t need8 = qkv_bytes + (size_t)8 * BB * CC * NN * 2 + (size_t)8 * BB * NN * 4;
    const size_t need4 = qkv_bytes + (size_t)4 * BB * CC * NN * 2 + (size_t)4 * BB * NN * 4;

    qkv_kernel<<<dim3(640), dim3(256), 0, stream>>>(X, Wq, bq, Wk, bk, Wv, bv, qw, kfrag, vfrag);

    if (ws_size >= need8) {
        attn_kernel<8, false><<<dim3(1024), dim3(256), 0, stream>>>(
            qw, kfrag, vfrag, pout, pl, X, gm, out);
        combine_kernel<8><<<dim3((BB * CC * NN / 4) / 256), dim3(256), 0, stream>>>(
            pout, pl, X, gm, out);
    } else if (ws_size >= need4) {
        float* pl4 = (float*)(pout + (size_t)4 * BB * CC * NN);
        attn_kernel<4, false><<<dim3(512), dim3(256), 0, stream>>>(
            qw, kfrag, vfrag, pout, pl4, X, gm, out);
        combine_kernel<4><<<dim3((BB * CC * NN / 4) / 256), dim3(256), 0, stream>>>(
            pout, pl4, X, gm, out);
    } else {
        attn_kernel<1, true><<<dim3(128), dim3(256), 0, stream>>>(
            qw, kfrag, vfrag, nullptr, nullptr, X, gm, out);
    }
}